// Round 10
// baseline (1279.169 us; speedup 1.0000x reference)
//
#include <hip/hip_runtime.h>
#include <math.h>

// Problem constants
#define BB 2
#define TT 2048
#define CC 768
#define HH 12
#define NN 64
#define GG 2
#define CG 384   // C/G
#define FF 3145728L   // B*C*T
#define S1 1572864L   // B*384*T

// ---------------------------------------------------------------------------
// Generic fp32 tiled GEMM v1: 64x64 tile, 256 threads, 4x4 micro-tile.
// Kept for small/odd shapes (M=64/192 loras, MODE3/4 epilogues).
// ---------------------------------------------------------------------------
template<int ATRANS, int BTRANS, int TOUT, int MODE>
__global__ __launch_bounds__(256) void gemm_kernel(
    const float* __restrict__ A, const float* __restrict__ Bm, float* __restrict__ Cm,
    const float* __restrict__ aux, const float* __restrict__ aux2,
    int K, int ldA, int ldB, int ldC, int zInner,
    long sA_o, long sA_i, long sB_o, long sB_i, long sC_o, long sC_i,
    long sAux_i, long sAux2_o)
{
    const int zo = blockIdx.z / zInner;
    const int zi = blockIdx.z % zInner;
    A  += (size_t)zo * sA_o + (size_t)zi * sA_i;
    Bm += (size_t)zo * sB_o + (size_t)zi * sB_i;
    Cm += (size_t)zo * sC_o + (size_t)zi * sC_i;
    if (MODE == 2) { aux += (size_t)zi * sAux_i; aux2 += (size_t)zo * sAux2_o; }

    const int m0t = blockIdx.y * 64;
    const int n0t = blockIdx.x * 64;
    const int tid = threadIdx.x;

    __shared__ float As[16][64];
    __shared__ float Bs[16][64];

    int mi, ni;
    if (TOUT) { mi = (tid & 15) * 4; ni = (tid >> 4) * 4; }
    else      { ni = (tid & 15) * 4; mi = (tid >> 4) * 4; }

    float acc[4][4];
#pragma unroll
    for (int i = 0; i < 4; ++i)
#pragma unroll
        for (int j = 0; j < 4; ++j) acc[i][j] = 0.f;

    for (int k0 = 0; k0 < K; k0 += 16) {
        if (!ATRANS) {
            const int row = tid >> 2;
            const int kc  = (tid & 3) * 4;
            float4 av = *(const float4*)&A[(size_t)(m0t + row) * ldA + k0 + kc];
            As[kc + 0][row] = av.x; As[kc + 1][row] = av.y;
            As[kc + 2][row] = av.z; As[kc + 3][row] = av.w;
        } else {
            const int krow = tid >> 4;
            const int mc   = (tid & 15) * 4;
            *(float4*)&As[krow][mc] = *(const float4*)&A[(size_t)(k0 + krow) * ldA + m0t + mc];
        }
        if (!BTRANS) {
            const int krow = tid >> 4;
            const int tc   = (tid & 15) * 4;
            *(float4*)&Bs[krow][tc] = *(const float4*)&Bm[(size_t)(k0 + krow) * ldB + n0t + tc];
        } else {
            const int trow = tid >> 2;
            const int kc   = (tid & 3) * 4;
            float4 bv = *(const float4*)&Bm[(size_t)(n0t + trow) * ldB + k0 + kc];
            Bs[kc + 0][trow] = bv.x; Bs[kc + 1][trow] = bv.y;
            Bs[kc + 2][trow] = bv.z; Bs[kc + 3][trow] = bv.w;
        }
        __syncthreads();
#pragma unroll
        for (int kk = 0; kk < 16; ++kk) {
            float4 a4 = *(const float4*)&As[kk][mi];
            float4 b4 = *(const float4*)&Bs[kk][ni];
            float am[4] = {a4.x, a4.y, a4.z, a4.w};
            float bn[4] = {b4.x, b4.y, b4.z, b4.w};
#pragma unroll
            for (int i = 0; i < 4; ++i)
#pragma unroll
                for (int j = 0; j < 4; ++j) acc[i][j] = fmaf(am[i], bn[j], acc[i][j]);
        }
        __syncthreads();
    }

    const int mbase = m0t + mi, nbase = n0t + ni;
#pragma unroll
    for (int i = 0; i < 4; ++i) {
        float4 xv;
        if (MODE == 2) xv = *(const float4*)&aux2[(size_t)(mbase + i) * ldC + nbase];
        float xa[4] = {0.f, 0.f, 0.f, 0.f};
        if (MODE == 2) { xa[0] = xv.x; xa[1] = xv.y; xa[2] = xv.z; xa[3] = xv.w; }
#pragma unroll
        for (int j = 0; j < 4; ++j) {
            float v = acc[i][j];
            if (MODE == 1) v = tanhf(v);
            else if (MODE == 2) v = xa[j] * (aux[mbase + i] + v);
            else if (MODE == 3) {
                float u  = aux[mbase + i] + v;
                float sp = fmaxf(-u, 0.f) + log1pf(expf(-fabsf(u)));  // softplus(-u)
                float wl = -sp - 0.5f;
                v = expf(-expf(wl));
            } else if (MODE == 4) {
                float u = aux[mbase + i] + v;
                v = 1.f / (1.f + expf(-u));
            }
            acc[i][j] = v;
        }
    }
    if (!TOUT) {
#pragma unroll
        for (int i = 0; i < 4; ++i) {
            float4 o = {acc[i][0], acc[i][1], acc[i][2], acc[i][3]};
            *(float4*)&Cm[(size_t)(mbase + i) * ldC + nbase] = o;
        }
    } else {
#pragma unroll
        for (int j = 0; j < 4; ++j) {
            float4 o = {acc[0][j], acc[1][j], acc[2][j], acc[3][j]};
            *(float4*)&Cm[(size_t)(nbase + j) * ldC + mbase] = o;
        }
    }
}

// ---------------------------------------------------------------------------
// GEMM v2: 128x128 tile, 256 threads, 8x8 micro-tile with SPLIT rows/cols
// (each thread owns rows {mi..mi+3, 64+mi..64+mi+3} x cols {ni.., 64+ni..})
// so every LDS read spans <=64 floats -> 2-way bank aliasing (free, m136).
// 4 ds_read_b128 per 64 fma = 0.5 B/FLOP: LDS-BW floor ~140us for the full
// stack vs ~280us for the 4x4 kernel. Used for the big regular GEMMs.
// ---------------------------------------------------------------------------
template<int ATRANS, int BTRANS, int TOUT, int MODE>
__global__ __launch_bounds__(256) void gemm2_kernel(
    const float* __restrict__ A, const float* __restrict__ Bm, float* __restrict__ Cm,
    const float* __restrict__ aux, const float* __restrict__ aux2,
    int K, int ldA, int ldB, int ldC, int zInner,
    long sA_o, long sA_i, long sB_o, long sB_i, long sC_o, long sC_i,
    long sAux_i, long sAux2_o)
{
    const int zo = blockIdx.z / zInner;
    const int zi = blockIdx.z % zInner;
    A  += (size_t)zo * sA_o + (size_t)zi * sA_i;
    Bm += (size_t)zo * sB_o + (size_t)zi * sB_i;
    Cm += (size_t)zo * sC_o + (size_t)zi * sC_i;
    if (MODE == 2) { aux += (size_t)zi * sAux_i; aux2 += (size_t)zo * sAux2_o; }

    const int m0 = blockIdx.y * 128;
    const int n0 = blockIdx.x * 128;
    const int tid = threadIdx.x;

    __shared__ float As[16][128];
    __shared__ float Bs[16][128];

    int mi4, ni4;
    if (TOUT) { mi4 = (tid & 15) * 4; ni4 = (tid >> 4) * 4; }
    else      { ni4 = (tid & 15) * 4; mi4 = (tid >> 4) * 4; }

    float acc[8][8];
#pragma unroll
    for (int i = 0; i < 8; ++i)
#pragma unroll
        for (int j = 0; j < 8; ++j) acc[i][j] = 0.f;

    for (int k0 = 0; k0 < K; k0 += 16) {
        // ---- stage A slab: As[k][m], m in [0,128)
        if (!ATRANS) {
            const int row = tid >> 1;            // 0..127
            const int kc  = (tid & 1) * 8;       // 0 or 8
            float4 a0 = *(const float4*)&A[(size_t)(m0 + row) * ldA + k0 + kc];
            float4 a1 = *(const float4*)&A[(size_t)(m0 + row) * ldA + k0 + kc + 4];
            As[kc + 0][row] = a0.x; As[kc + 1][row] = a0.y;
            As[kc + 2][row] = a0.z; As[kc + 3][row] = a0.w;
            As[kc + 4][row] = a1.x; As[kc + 5][row] = a1.y;
            As[kc + 6][row] = a1.z; As[kc + 7][row] = a1.w;
        } else {
            const int krow = tid >> 4;           // 0..15
            const int mc   = (tid & 15) * 8;
            *(float4*)&As[krow][mc]     = *(const float4*)&A[(size_t)(k0 + krow) * ldA + m0 + mc];
            *(float4*)&As[krow][mc + 4] = *(const float4*)&A[(size_t)(k0 + krow) * ldA + m0 + mc + 4];
        }
        // ---- stage B slab: Bs[k][n], n in [0,128)
        if (!BTRANS) {
            const int krow = tid >> 4;
            const int tc   = (tid & 15) * 8;
            *(float4*)&Bs[krow][tc]     = *(const float4*)&Bm[(size_t)(k0 + krow) * ldB + n0 + tc];
            *(float4*)&Bs[krow][tc + 4] = *(const float4*)&Bm[(size_t)(k0 + krow) * ldB + n0 + tc + 4];
        } else {
            const int trow = tid >> 1;
            const int kc   = (tid & 1) * 8;
            float4 b0 = *(const float4*)&Bm[(size_t)(n0 + trow) * ldB + k0 + kc];
            float4 b1 = *(const float4*)&Bm[(size_t)(n0 + trow) * ldB + k0 + kc + 4];
            Bs[kc + 0][trow] = b0.x; Bs[kc + 1][trow] = b0.y;
            Bs[kc + 2][trow] = b0.z; Bs[kc + 3][trow] = b0.w;
            Bs[kc + 4][trow] = b1.x; Bs[kc + 5][trow] = b1.y;
            Bs[kc + 6][trow] = b1.z; Bs[kc + 7][trow] = b1.w;
        }
        __syncthreads();
#pragma unroll
        for (int kk = 0; kk < 16; ++kk) {
            float4 alo = *(const float4*)&As[kk][mi4];
            float4 ahi = *(const float4*)&As[kk][64 + mi4];
            float4 blo = *(const float4*)&Bs[kk][ni4];
            float4 bhi = *(const float4*)&Bs[kk][64 + ni4];
            float am[8] = {alo.x, alo.y, alo.z, alo.w, ahi.x, ahi.y, ahi.z, ahi.w};
            float bn[8] = {blo.x, blo.y, blo.z, blo.w, bhi.x, bhi.y, bhi.z, bhi.w};
#pragma unroll
            for (int i = 0; i < 8; ++i)
#pragma unroll
                for (int j = 0; j < 8; ++j) acc[i][j] = fmaf(am[i], bn[j], acc[i][j]);
        }
        __syncthreads();
    }

    // row/col maps for the split micro-tile
    int mrow[8], ncl = n0 + ni4, nch = n0 + 64 + ni4;
#pragma unroll
    for (int i = 0; i < 4; ++i) { mrow[i] = m0 + mi4 + i; mrow[i + 4] = m0 + 64 + mi4 + i; }

    // epilogue transforms
#pragma unroll
    for (int i = 0; i < 8; ++i) {
        float xa[8];
        if (MODE == 2) {
            float4 xlo = *(const float4*)&aux2[(size_t)mrow[i] * ldC + ncl];
            float4 xhi = *(const float4*)&aux2[(size_t)mrow[i] * ldC + nch];
            xa[0] = xlo.x; xa[1] = xlo.y; xa[2] = xlo.z; xa[3] = xlo.w;
            xa[4] = xhi.x; xa[5] = xhi.y; xa[6] = xhi.z; xa[7] = xhi.w;
        }
#pragma unroll
        for (int j = 0; j < 8; ++j) {
            float v = acc[i][j];
            if (MODE == 1) v = tanhf(v);
            else if (MODE == 2) v = xa[j] * (aux[mrow[i]] + v);
            acc[i][j] = v;
        }
    }
    if (!TOUT) {
#pragma unroll
        for (int i = 0; i < 8; ++i) {
            float4 o0 = {acc[i][0], acc[i][1], acc[i][2], acc[i][3]};
            float4 o1 = {acc[i][4], acc[i][5], acc[i][6], acc[i][7]};
            *(float4*)&Cm[(size_t)mrow[i] * ldC + ncl] = o0;
            *(float4*)&Cm[(size_t)mrow[i] * ldC + nch] = o1;
        }
    } else {
#pragma unroll
        for (int j = 0; j < 8; ++j) {
            const int col = (j < 4) ? (n0 + ni4 + j) : (n0 + 64 + ni4 + j - 4);
            float4 o0 = {acc[0][j], acc[1][j], acc[2][j], acc[3][j]};
            float4 o1 = {acc[4][j], acc[5][j], acc[6][j], acc[7][j]};
            *(float4*)&Cm[(size_t)col * ldC + m0 + mi4]      = o0;
            *(float4*)&Cm[(size_t)col * ldC + m0 + 64 + mi4] = o1;
        }
    }
}

// ---------------------------------------------------------------------------
__global__ void pack_aux_kernel(const float* __restrict__ r, const float* __restrict__ w,
                                const float* __restrict__ k, const float* __restrict__ v,
                                const float* __restrict__ a, const float* __restrict__ g,
                                float* __restrict__ paux)
{
    int c = blockIdx.x * blockDim.x + threadIdx.x;
    if (c < CC) {
        paux[0 * CC + c] = 1.f + r[c];
        paux[1 * CC + c] = 1.f + w[c];
        paux[2 * CC + c] = 1.f + k[c];
        paux[3 * CC + c] = 1.f + v[c];
        paux[4 * CC + c] = 1.f + a[c];
        paux[5 * CC + c] = 1.f + g[c];
    }
}

// ---------------------------------------------------------------------------
// E1: per token, kk = k + kvec; per-head L2-normalize; aa=-kkn, b2=kkn*a.
// ---------------------------------------------------------------------------
__global__ __launch_bounds__(256) void e1_kernel(const float* __restrict__ kA,
                                                 float* __restrict__ kvecA,
                                                 float* __restrict__ aA)
{
    const size_t base = (size_t)blockIdx.x * CC;
    const int tid = threadIdx.x;
#pragma unroll
    for (int ch = 0; ch < 3; ++ch) {
        int c = ch * 256 + tid;
        float kk = kA[base + c] + kvecA[base + c];
        float ss = kk * kk;
#pragma unroll
        for (int off = 32; off; off >>= 1) ss += __shfl_xor(ss, off, 64);
        float denom = fmaxf(sqrtf(ss), 1e-12f);
        float kkn = kk / denom;
        float av = aA[base + c];
        kvecA[base + c] = -kkn;       // aa
        aA[base + c]    = kkn * av;   // b2
    }
}

// ---------------------------------------------------------------------------
// WKV-7 recurrence, v9 (unchanged from round 9, 550us steady): 8-way column
// split, 192 waves, SADDR 32-bit addressing, 3-deep named-fragment prefetch.
// ---------------------------------------------------------------------------
struct WFrag {
    float4 w[2], a[2], b[2], k[2], r[2];
    float vv;
};

__global__ __launch_bounds__(64) void wkv_kernel(
    const float* __restrict__ rA, const float* __restrict__ wA,
    const float* __restrict__ kA, const float* __restrict__ vA,
    const float* __restrict__ aaA, const float* __restrict__ b2A,
    float* __restrict__ yA)
{
    const int blk = blockIdx.x;          // rg*24 + bh  (XCD swizzle)
    const int bh = blk % 24, rg = blk / 24;
    const int b = bh / HH, h = bh - b * HH;
    const int lane = threadIdx.x;
    const int jg = lane >> 3, p = lane & 7;
    const int row = rg * 8 + p;
    const int base = b * TT * CC + h * NN;
    const int fo = jg * 8;

    float S[8];
#pragma unroll
    for (int i = 0; i < 8; ++i) S[i] = 0.f;

    WFrag f0, f1, f2;

    auto loadfrag = [&](WFrag& f, int t) {
        const int o = base + t * CC + fo;
#pragma unroll
        for (int q = 0; q < 2; ++q) {
            f.w[q] = *(const float4*)&wA[o + 4 * q];
            f.a[q] = *(const float4*)&aaA[o + 4 * q];
            f.b[q] = *(const float4*)&b2A[o + 4 * q];
            f.k[q] = *(const float4*)&kA[o + 4 * q];
            f.r[q] = *(const float4*)&rA[o + 4 * q];
        }
        f.vv = vA[base + t * CC + row];
    };

    auto stepf = [&](const WFrag& f, int t) {
        const float vv = f.vv;
        float vk[8];
#pragma unroll
        for (int q = 0; q < 2; ++q) {
            vk[4*q+0] = vv * f.k[q].x;
            vk[4*q+1] = vv * f.k[q].y;
            vk[4*q+2] = vv * f.k[q].z;
            vk[4*q+3] = vv * f.k[q].w;
        }

        float t0 = 0.f, t1 = 0.f, t2 = 0.f, t3 = 0.f;
#pragma unroll
        for (int q = 0; q < 2; ++q) {
            float4 a4 = f.a[q];
            t0 = fmaf(S[4*q+0], a4.x, t0);
            t1 = fmaf(S[4*q+1], a4.y, t1);
            t2 = fmaf(S[4*q+2], a4.z, t2);
            t3 = fmaf(S[4*q+3], a4.w, t3);
        }
        float part = (t0 + t1) + (t2 + t3);
        float s08 = __shfl_xor(part,  8, 64);
        float s16 = __shfl_xor(part, 16, 64);
        float s24 = __shfl_xor(part, 24, 64);
        float s32 = __shfl_xor(part, 32, 64);
        float s40 = __shfl_xor(part, 40, 64);
        float s48 = __shfl_xor(part, 48, 64);
        float s56 = __shfl_xor(part, 56, 64);
        float tmp = ((part + s08) + (s16 + s24)) + ((s32 + s40) + (s48 + s56));

        float y0 = 0.f, y1 = 0.f, y2 = 0.f, y3 = 0.f;
#pragma unroll
        for (int q = 0; q < 2; ++q) {
            float4 w4 = f.w[q], b4 = f.b[q], r4 = f.r[q];
            S[4*q+0] = fmaf(S[4*q+0], w4.x, fmaf(tmp, b4.x, vk[4*q+0]));
            y0 = fmaf(S[4*q+0], r4.x, y0);
            S[4*q+1] = fmaf(S[4*q+1], w4.y, fmaf(tmp, b4.y, vk[4*q+1]));
            y1 = fmaf(S[4*q+1], r4.y, y1);
            S[4*q+2] = fmaf(S[4*q+2], w4.z, fmaf(tmp, b4.z, vk[4*q+2]));
            y2 = fmaf(S[4*q+2], r4.z, y2);
            S[4*q+3] = fmaf(S[4*q+3], w4.w, fmaf(tmp, b4.w, vk[4*q+3]));
            y3 = fmaf(S[4*q+3], r4.w, y3);
        }
        float yp = (y0 + y1) + (y2 + y3);
        float u08 = __shfl_xor(yp,  8, 64);
        float u16 = __shfl_xor(yp, 16, 64);
        float u24 = __shfl_xor(yp, 24, 64);
        float u32 = __shfl_xor(yp, 32, 64);
        float u40 = __shfl_xor(yp, 40, 64);
        float u48 = __shfl_xor(yp, 48, 64);
        float u56 = __shfl_xor(yp, 56, 64);
        float y = ((yp + u08) + (u16 + u24)) + ((u32 + u40) + (u48 + u56));
        if (jg == 0) yA[base + t * CC + row] = y;
    };

    loadfrag(f0, 0);
    loadfrag(f1, 1);
    loadfrag(f2, 2);

    int t = 0;
    for (; t + 2 < TT; t += 3) {
        stepf(f0, t);
        if (t + 3 < TT) loadfrag(f0, t + 3);
        stepf(f1, t + 1);
        if (t + 4 < TT) loadfrag(f1, t + 4);
        stepf(f2, t + 2);
        if (t + 5 < TT) loadfrag(f2, t + 5);
    }
    if (t < TT) stepf(f0, t);
    if (t + 1 < TT) stepf(f1, t + 1);
}

// ---------------------------------------------------------------------------
// E2: per token: RMSNorm(y)*lnw + (sum_head r*k*faaaa)*v, times g, write (B,T,C)
// ---------------------------------------------------------------------------
__global__ __launch_bounds__(256) void e2_kernel(
    const float* __restrict__ yA, const float* __restrict__ rA,
    const float* __restrict__ kA, const float* __restrict__ vA,
    const float* __restrict__ gA, const float* __restrict__ faaaa,
    const float* __restrict__ lnw, float* __restrict__ zA)
{
    const size_t base = (size_t)blockIdx.x * CC;
    const int tid = threadIdx.x;
    const int wave = tid >> 6;
    __shared__ float red[4];
    __shared__ float rk[12];

    float yv[3];
    float ss = 0.f;
#pragma unroll
    for (int ch = 0; ch < 3; ++ch) {
        int c = ch * 256 + tid;
        float y = yA[base + c];
        yv[ch] = y;
        ss = fmaf(y, y, ss);
        float p = rA[base + c] * kA[base + c] * faaaa[c];
#pragma unroll
        for (int off = 32; off; off >>= 1) p += __shfl_xor(p, off, 64);
        if ((tid & 63) == 0) rk[ch * 4 + wave] = p;
    }
#pragma unroll
    for (int off = 32; off; off >>= 1) ss += __shfl_xor(ss, off, 64);
    if ((tid & 63) == 0) red[wave] = ss;
    __syncthreads();
    const float total = red[0] + red[1] + red[2] + red[3];
    const float scale = rsqrtf(total / (float)CC + 1e-5f);
#pragma unroll
    for (int ch = 0; ch < 3; ++ch) {
        int c = ch * 256 + tid;
        float out = yv[ch] * scale * lnw[c] + rk[c >> 6] * vA[base + c];
        zA[base + c] = out * gA[base + c];
    }
}

// ---------------------------------------------------------------------------
extern "C" void kernel_launch(void* const* d_in, const int* in_sizes, int n_in,
                              void* d_out, int out_size, void* d_ws, size_t ws_size,
                              hipStream_t stream)
{
    (void)in_sizes; (void)n_in; (void)out_size; (void)ws_size;
    const float* x        = (const float*)d_in[0];
    const float* tmaa_r   = (const float*)d_in[2];
    const float* tmaa_w   = (const float*)d_in[3];
    const float* tmaa_k   = (const float*)d_in[4];
    const float* tmaa_v   = (const float*)d_in[5];
    const float* tmaa_a   = (const float*)d_in[6];
    const float* tmaa_g   = (const float*)d_in[7];
    const float* tdecay   = (const float*)d_in[8];
    const float* tfaaaa   = (const float*)d_in[9];
    const float* taaaaa   = (const float*)d_in[10];
    const float* maa_w1   = (const float*)d_in[11];
    const float* maa_w2   = (const float*)d_in[12];
    const float* decay_w1 = (const float*)d_in[13];
    const float* decay_w2 = (const float*)d_in[14];
    const float* aaa_w1   = (const float*)d_in[15];
    const float* aaa_w2   = (const float*)d_in[16];
    const float* kkk_w1   = (const float*)d_in[17];
    const float* kkk_w2   = (const float*)d_in[18];
    const float* gate_w1  = (const float*)d_in[19];
    const float* gate_w2  = (const float*)d_in[20];
    const float* w_key    = (const float*)d_in[21];
    const float* w_value  = (const float*)d_in[22];
    const float* w_recept = (const float*)d_in[23];
    const float* w_output = (const float*)d_in[24];
    const float* lnw      = (const float*)d_in[25];
    float* out = (float*)d_out;

    float* ws   = (float*)d_ws;
    float* paux = ws;                 // 6*768
    float* tm   = ws + 8192;          // S1
    float* X6   = tm + S1;            // 6*FF
    float* dh   = X6 + 6 * FF;        // B*64*T = 262144
    float* ah   = dh + 262144;
    float* kh   = ah + 262144;
    float* gh   = kh + 262144;        // B*192*T = 786432
    float* gbuf = gh + 786432;        // FF
    float* ybuf = gbuf + FF;          // FF
    float* zbuf = ybuf + FF;          // FF

    float* xr = X6 + 0 * FF; float* xw = X6 + 1 * FF; float* xk = X6 + 2 * FF;
    float* xv = X6 + 3 * FF; float* xa = X6 + 4 * FF; float* xg = X6 + 5 * FF;
    float* wwB = X6 + 0 * FF; float* rB  = X6 + 1 * FF; float* aaB = X6 + 2 * FF;
    float* b2B = X6 + 3 * FF; float* kB  = X6 + 4 * FF; float* vB  = X6 + 5 * FF;

    const long CT = (long)CC * TT;        // 1572864
    const long TC = (long)TT * CC;        // 1572864

    pack_aux_kernel<<<dim3(3), 256, 0, stream>>>(tmaa_r, tmaa_w, tmaa_k, tmaa_v, tmaa_a, tmaa_g, paux);

    // tm = tanh(maa_w1 @ x)   (B,384,T)   [gemm2: M=384,N=2048,K=768]
    gemm2_kernel<0,0,0,1><<<dim3(16, 3, 2), 256, 0, stream>>>(
        maa_w1, x, tm, nullptr, nullptr,
        768, 768, TT, TT, 1,
        0, 0, CT, 0, 384L * TT, 0, 0, 0);

    // X6[n] = x * (paux[n] + maa_w2[n]^T @ tm_n)   z = b*6 + n  [gemm2: M=768,K=64]
    gemm2_kernel<1,0,0,2><<<dim3(16, 6, 12), 256, 0, stream>>>(
        maa_w2, tm, X6, paux, x,
        64, 768, TT, TT, 6,
        0, 64L * 768, 384L * TT, 64L * TT, CT, FF, 768, CT);

    // lora hiddens (tanh) — small M, keep v1
    gemm_kernel<0,0,0,1><<<dim3(32, 1, 2), 256, 0, stream>>>(
        decay_w1, xw, dh, nullptr, nullptr, 768, 768, TT, TT, 1,
        0, 0, CT, 0, 64L * TT, 0, 0, 0);
    gemm_kernel<0,0,0,1><<<dim3(32, 1, 2), 256, 0, stream>>>(
        aaa_w1, xa, ah, nullptr, nullptr, 768, 768, TT, TT, 1,
        0, 0, CT, 0, 64L * TT, 0, 0, 0);
    gemm_kernel<0,0,0,1><<<dim3(32, 1, 2), 256, 0, stream>>>(
        kkk_w1, xk, kh, nullptr, nullptr, 768, 768, TT, TT, 1,
        0, 0, CT, 0, 64L * TT, 0, 0, 0);
    gemm_kernel<0,0,0,1><<<dim3(32, 3, 2), 256, 0, stream>>>(
        gate_w1, xg, gh, nullptr, nullptr, 768, 768, TT, TT, 1,
        0, 0, CT, 0, 192L * TT, 0, 0, 0);

    // grouped convs -> (B,T,C) transposed outputs. z = b*2 + g  [gemm2: M=384,K=384]
    gemm2_kernel<0,0,1,0><<<dim3(16, 3, 4), 256, 0, stream>>>(
        w_recept, xr, rB, nullptr, nullptr, 384, 384, TT, CC, 2,
        0, 384L * 384, CT, 384L * TT, TC, 384, 0, 0);
    gemm2_kernel<0,0,1,0><<<dim3(16, 3, 4), 256, 0, stream>>>(
        w_key, xk, kB, nullptr, nullptr, 384, 384, TT, CC, 2,
        0, 384L * 384, CT, 384L * TT, TC, 384, 0, 0);
    gemm2_kernel<0,0,1,0><<<dim3(16, 3, 4), 256, 0, stream>>>(
        w_value, xv, vB, nullptr, nullptr, 384, 384, TT, CC, 2,
        0, 384L * 384, CT, 384L * TT, TC, 384, 0, 0);

    // lora outs -> (B,T,C)
    gemm_kernel<0,0,1,3><<<dim3(32, 12, 2), 256, 0, stream>>>(
        decay_w2, dh, wwB, tdecay, nullptr, 64, 64, TT, CC, 1,
        0, 0, 64L * TT, 0, TC, 0, 0, 0);
    gemm_kernel<0,0,1,4><<<dim3(32, 12, 2), 256, 0, stream>>>(
        aaa_w2, ah, b2B /* a for now */, taaaaa, nullptr, 64, 64, TT, CC, 1,
        0, 0, 64L * TT, 0, TC, 0, 0, 0);
    gemm2_kernel<0,0,1,0><<<dim3(16, 6, 2), 256, 0, stream>>>(
        kkk_w2, kh, aaB /* kvec for now */, nullptr, nullptr, 64, 64, TT, CC, 1,
        0, 0, 64L * TT, 0, TC, 0, 0, 0);
    gemm2_kernel<0,0,1,0><<<dim3(16, 6, 2), 256, 0, stream>>>(
        gate_w2, gh, gbuf, nullptr, nullptr, 192, 192, TT, CC, 1,
        0, 0, 192L * TT, 0, TC, 0, 0, 0);

    // E1: build aa (over kvec slot) and b2 (over a slot)
    e1_kernel<<<dim3(BB * TT), 256, 0, stream>>>(kB, aaB, b2B);

    // WKV recurrence v9: 8-way column split, 192 waves
    wkv_kernel<<<dim3(BB * HH * 8), 64, 0, stream>>>(rB, wwB, kB, vB, aaB, b2B, ybuf);

    // E2: rmsnorm + faaaa bonus + gate
    e2_kernel<<<dim3(BB * TT), 256, 0, stream>>>(ybuf, rB, kB, vB, gbuf, tfaaaa, lnw, zbuf);

    // final grouped conv from (B,T,C) z -> (B,C,T) out.  z = b*2 + g  [gemm2, BTRANS]
    gemm2_kernel<0,1,0,0><<<dim3(16, 3, 4), 256, 0, stream>>>(
        w_output, zbuf, out, nullptr, nullptr, 384, 384, CC, TT, 2,
        0, 384L * 384, TC, 384, CT, 384L * TT, 0, 0);
}

// Round 11
// 1057.995 us; speedup vs baseline: 1.2091x; 1.2091x over previous
//
#include <hip/hip_runtime.h>
#include <math.h>

// Problem constants
#define BB 2
#define TT 2048
#define CC 768
#define HH 12
#define NN 64
#define GG 2
#define CG 384   // C/G
#define FF 3145728L   // B*C*T
#define S1 1572864L   // B*384*T

typedef __attribute__((ext_vector_type(8))) short bf8frag;   // 8 bf16 (4 VGPRs)
typedef __attribute__((ext_vector_type(4))) float f4acc;     // 4 fp32 acc

__device__ inline unsigned short f2bf(float x) {
    union { float f; unsigned u; } v; v.f = x;
    unsigned r = v.u + 0x7FFFu + ((v.u >> 16) & 1u);   // RNE
    return (unsigned short)(r >> 16);
}

// ---------------------------------------------------------------------------
// Generic fp32 tiled GEMM v1: 64x64 tile, 256 threads, 4x4 micro-tile.
// (Round-9 proven config; gemm2 128-tile regressed via under-occupancy.)
// bfout: optional bf16 side-write base (used by the mix GEMM to emit bf16
// copies of xr/xk/xv for the MFMA convs).
// ---------------------------------------------------------------------------
template<int ATRANS, int BTRANS, int TOUT, int MODE>
__global__ __launch_bounds__(256) void gemm_kernel(
    const float* __restrict__ A, const float* __restrict__ Bm, float* __restrict__ Cm,
    const float* __restrict__ aux, const float* __restrict__ aux2,
    int K, int ldA, int ldB, int ldC, int zInner,
    long sA_o, long sA_i, long sB_o, long sB_i, long sC_o, long sC_i,
    long sAux_i, long sAux2_o, unsigned short* bfout)
{
    const int zo = blockIdx.z / zInner;
    const int zi = blockIdx.z % zInner;
    A  += (size_t)zo * sA_o + (size_t)zi * sA_i;
    Bm += (size_t)zo * sB_o + (size_t)zi * sB_i;
    Cm += (size_t)zo * sC_o + (size_t)zi * sC_i;
    if (MODE == 2) { aux += (size_t)zi * sAux_i; aux2 += (size_t)zo * sAux2_o; }

    const int m0t = blockIdx.y * 64;
    const int n0t = blockIdx.x * 64;
    const int tid = threadIdx.x;

    __shared__ float As[16][64];
    __shared__ float Bs[16][64];

    int mi, ni;
    if (TOUT) { mi = (tid & 15) * 4; ni = (tid >> 4) * 4; }
    else      { ni = (tid & 15) * 4; mi = (tid >> 4) * 4; }

    float acc[4][4];
#pragma unroll
    for (int i = 0; i < 4; ++i)
#pragma unroll
        for (int j = 0; j < 4; ++j) acc[i][j] = 0.f;

    for (int k0 = 0; k0 < K; k0 += 16) {
        if (!ATRANS) {
            const int row = tid >> 2;
            const int kc  = (tid & 3) * 4;
            float4 av = *(const float4*)&A[(size_t)(m0t + row) * ldA + k0 + kc];
            As[kc + 0][row] = av.x; As[kc + 1][row] = av.y;
            As[kc + 2][row] = av.z; As[kc + 3][row] = av.w;
        } else {
            const int krow = tid >> 4;
            const int mc   = (tid & 15) * 4;
            *(float4*)&As[krow][mc] = *(const float4*)&A[(size_t)(k0 + krow) * ldA + m0t + mc];
        }
        if (!BTRANS) {
            const int krow = tid >> 4;
            const int tc   = (tid & 15) * 4;
            *(float4*)&Bs[krow][tc] = *(const float4*)&Bm[(size_t)(k0 + krow) * ldB + n0t + tc];
        } else {
            const int trow = tid >> 2;
            const int kc   = (tid & 3) * 4;
            float4 bv = *(const float4*)&Bm[(size_t)(n0t + trow) * ldB + k0 + kc];
            Bs[kc + 0][trow] = bv.x; Bs[kc + 1][trow] = bv.y;
            Bs[kc + 2][trow] = bv.z; Bs[kc + 3][trow] = bv.w;
        }
        __syncthreads();
#pragma unroll
        for (int kk = 0; kk < 16; ++kk) {
            float4 a4 = *(const float4*)&As[kk][mi];
            float4 b4 = *(const float4*)&Bs[kk][ni];
            float am[4] = {a4.x, a4.y, a4.z, a4.w};
            float bn[4] = {b4.x, b4.y, b4.z, b4.w};
#pragma unroll
            for (int i = 0; i < 4; ++i)
#pragma unroll
                for (int j = 0; j < 4; ++j) acc[i][j] = fmaf(am[i], bn[j], acc[i][j]);
        }
        __syncthreads();
    }

    const int mbase = m0t + mi, nbase = n0t + ni;
#pragma unroll
    for (int i = 0; i < 4; ++i) {
        float4 xv;
        if (MODE == 2) xv = *(const float4*)&aux2[(size_t)(mbase + i) * ldC + nbase];
        float xa[4] = {0.f, 0.f, 0.f, 0.f};
        if (MODE == 2) { xa[0] = xv.x; xa[1] = xv.y; xa[2] = xv.z; xa[3] = xv.w; }
#pragma unroll
        for (int j = 0; j < 4; ++j) {
            float v = acc[i][j];
            if (MODE == 1) v = tanhf(v);
            else if (MODE == 2) v = xa[j] * (aux[mbase + i] + v);
            else if (MODE == 3) {
                float u  = aux[mbase + i] + v;
                float sp = fmaxf(-u, 0.f) + log1pf(expf(-fabsf(u)));  // softplus(-u)
                float wl = -sp - 0.5f;
                v = expf(-expf(wl));
            } else if (MODE == 4) {
                float u = aux[mbase + i] + v;
                v = 1.f / (1.f + expf(-u));
            }
            acc[i][j] = v;
        }
    }
    if (!TOUT) {
#pragma unroll
        for (int i = 0; i < 4; ++i) {
            float4 o = {acc[i][0], acc[i][1], acc[i][2], acc[i][3]};
            *(float4*)&Cm[(size_t)(mbase + i) * ldC + nbase] = o;
        }
        // bf16 side-write for MFMA conv inputs: slots n in {0:xr, 2:xk, 3:xv}
        if (MODE == 2 && bfout != nullptr) {
            int sidx = (zi == 0) ? 0 : (zi == 2) ? 1 : (zi == 3) ? 2 : -1;
            if (sidx >= 0) {
                unsigned short* bp = bfout + (size_t)sidx * FF + (size_t)zo * ((long)CC * TT);
#pragma unroll
                for (int i = 0; i < 4; ++i) {
                    ushort4 o = {f2bf(acc[i][0]), f2bf(acc[i][1]), f2bf(acc[i][2]), f2bf(acc[i][3])};
                    *(ushort4*)&bp[(size_t)(mbase + i) * ldC + nbase] = o;
                }
            }
        }
    } else {
#pragma unroll
        for (int j = 0; j < 4; ++j) {
            float4 o = {acc[0][j], acc[1][j], acc[2][j], acc[3][j]};
            *(float4*)&Cm[(size_t)(nbase + j) * ldC + mbase] = o;
        }
    }
}

// ---------------------------------------------------------------------------
// bf16 MFMA grouped-conv GEMM: per (b,g), C(384 x 2048) = W(384x384) X(384x2048).
// Block = 128 out-ch x 128 t, 4 waves; wave w covers rows [32w,32w+32) as 2
// m-frags x 8 n-frags of 16x16x32 MFMA. LDS tiles padded to 40 (16B-aligned,
// bank-spread). Layouts (guide-verified): A[m=lane&15][k=quad*8+j],
// B[k=quad*8+j][n=lane&15], D[row=quad*4+i][col=lane&15].
//  XT=0: X stored (C,T) bf16 (input convs)  -> transpose-stage Xs[t][k]
//  XT=1: X stored (T,C) bf16 (output conv)  -> direct b128 stage
//  OUT_CT=0: store (B,T,C) fp32 (float4, contiguous c) ; =1: store (B,C,T)
// ---------------------------------------------------------------------------
template<int XT, int OUT_CT>
__global__ __launch_bounds__(256) void conv_mfma_kernel(
    const unsigned short* __restrict__ Wb, const unsigned short* __restrict__ Xb,
    float* __restrict__ Cout)
{
    const int bz = blockIdx.z; const int b = bz >> 1, g = bz & 1;
    const int t0 = blockIdx.x * 128;
    const int m0 = blockIdx.y * 128;
    const int tid = threadIdx.x;
    const int wave = tid >> 6, lane = tid & 63;
    const int lq = lane >> 4, lr = lane & 15;

    __shared__ unsigned short Ws[128 * 40];
    __shared__ unsigned short Xs[128 * 40];

    const unsigned short* Wg = Wb + (size_t)g * (CG * CG);
    const long xbase = XT ? ((long)b * (long)TT * CC)
                          : ((long)b * (long)CC * TT + (long)g * CG * TT);

    f4acc acc0[8], acc1[8];
#pragma unroll
    for (int j = 0; j < 8; ++j) { acc0[j] = (f4acc)0.f; acc1[j] = (f4acc)0.f; }

    for (int k0 = 0; k0 < CG; k0 += 32) {
        // stage W: rows m0..m0+127, k0..k0+31  (contiguous b128s)
        {
            const int m = tid >> 1, kc = (tid & 1) * 16;
            const unsigned short* src = Wg + (size_t)(m0 + m) * CG + k0 + kc;
            *(bf8frag*)&Ws[m * 40 + kc]     = *(const bf8frag*)src;
            *(bf8frag*)&Ws[m * 40 + kc + 8] = *(const bf8frag*)(src + 8);
        }
        // stage X -> Xs[t][k]
        if (!XT) {
            const int k = tid >> 3, te = (tid & 7) * 16;
            const unsigned short* src = Xb + xbase + (long)(k0 + k) * TT + t0 + te;
            bf8frag g1 = *(const bf8frag*)src;
            bf8frag g2 = *(const bf8frag*)(src + 8);
#pragma unroll
            for (int e = 0; e < 8; ++e) Xs[(te + e) * 40 + k] = (unsigned short)g1[e];
#pragma unroll
            for (int e = 0; e < 8; ++e) Xs[(te + 8 + e) * 40 + k] = (unsigned short)g2[e];
        } else {
            const int t = tid >> 1, kc = (tid & 1) * 16;
            const unsigned short* src = Xb + xbase + (long)(t0 + t) * CC + g * CG + k0 + kc;
            *(bf8frag*)&Xs[t * 40 + kc]     = *(const bf8frag*)src;
            *(bf8frag*)&Xs[t * 40 + kc + 8] = *(const bf8frag*)(src + 8);
        }
        __syncthreads();

        bf8frag a0 = *(const bf8frag*)&Ws[(32 * wave + lr) * 40 + lq * 8];
        bf8frag a1 = *(const bf8frag*)&Ws[(32 * wave + 16 + lr) * 40 + lq * 8];
#pragma unroll
        for (int nj = 0; nj < 8; ++nj) {
            bf8frag bb = *(const bf8frag*)&Xs[(16 * nj + lr) * 40 + lq * 8];
            acc0[nj] = __builtin_amdgcn_mfma_f32_16x16x32_bf16(a0, bb, acc0[nj], 0, 0, 0);
            acc1[nj] = __builtin_amdgcn_mfma_f32_16x16x32_bf16(a1, bb, acc1[nj], 0, 0, 0);
        }
        __syncthreads();
    }

    // epilogue: D row = lq*4+i, col = lane&15
#pragma unroll
    for (int fi = 0; fi < 2; ++fi) {
        const int cbase = m0 + 32 * wave + 16 * fi + lq * 4;
#pragma unroll
        for (int nj = 0; nj < 8; ++nj) {
            const f4acc av = fi ? acc1[nj] : acc0[nj];
            const int t = t0 + 16 * nj + lr;
            if (!OUT_CT) {
                float4 o = {av[0], av[1], av[2], av[3]};
                *(float4*)&Cout[(long)b * (long)TT * CC + (long)t * CC + g * CG + cbase] = o;
            } else {
#pragma unroll
                for (int i = 0; i < 4; ++i)
                    Cout[(long)b * (long)CC * TT + (long)(g * CG + cbase + i) * TT + t] = av[i];
            }
        }
    }
}

// ---------------------------------------------------------------------------
// Convert the 4 conv weight tensors (each (2,384,384) fp32) to bf16.
// Layout in wb: [conv 0..3][g][out][in], conv order: recept, key, value, output
// ---------------------------------------------------------------------------
__global__ void wcvt_kernel(const float* __restrict__ w0, const float* __restrict__ w1,
                            const float* __restrict__ w2, const float* __restrict__ w3,
                            unsigned short* __restrict__ wb)
{
    const int i = blockIdx.x * 256 + threadIdx.x;   // total 4*294912
    const int which = i / 294912, r = i - which * 294912;
    const float* s = (which == 0) ? w0 : (which == 1) ? w1 : (which == 2) ? w2 : w3;
    wb[i] = f2bf(s[r]);
}

// ---------------------------------------------------------------------------
__global__ void pack_aux_kernel(const float* __restrict__ r, const float* __restrict__ w,
                                const float* __restrict__ k, const float* __restrict__ v,
                                const float* __restrict__ a, const float* __restrict__ g,
                                float* __restrict__ paux)
{
    int c = blockIdx.x * blockDim.x + threadIdx.x;
    if (c < CC) {
        paux[0 * CC + c] = 1.f + r[c];
        paux[1 * CC + c] = 1.f + w[c];
        paux[2 * CC + c] = 1.f + k[c];
        paux[3 * CC + c] = 1.f + v[c];
        paux[4 * CC + c] = 1.f + a[c];
        paux[5 * CC + c] = 1.f + g[c];
    }
}

// ---------------------------------------------------------------------------
// E1: per token, kk = k + kvec; per-head L2-normalize; aa=-kkn, b2=kkn*a.
// ---------------------------------------------------------------------------
__global__ __launch_bounds__(256) void e1_kernel(const float* __restrict__ kA,
                                                 float* __restrict__ kvecA,
                                                 float* __restrict__ aA)
{
    const size_t base = (size_t)blockIdx.x * CC;
    const int tid = threadIdx.x;
#pragma unroll
    for (int ch = 0; ch < 3; ++ch) {
        int c = ch * 256 + tid;
        float kk = kA[base + c] + kvecA[base + c];
        float ss = kk * kk;
#pragma unroll
        for (int off = 32; off; off >>= 1) ss += __shfl_xor(ss, off, 64);
        float denom = fmaxf(sqrtf(ss), 1e-12f);
        float kkn = kk / denom;
        float av = aA[base + c];
        kvecA[base + c] = -kkn;       // aa
        aA[base + c]    = kkn * av;   // b2
    }
}

// ---------------------------------------------------------------------------
// WKV-7 recurrence, v9 (unchanged, 545us steady): 8-way column split,
// 192 waves, SADDR 32-bit addressing, 3-deep named-fragment prefetch.
// ---------------------------------------------------------------------------
struct WFrag {
    float4 w[2], a[2], b[2], k[2], r[2];
    float vv;
};

__global__ __launch_bounds__(64) void wkv_kernel(
    const float* __restrict__ rA, const float* __restrict__ wA,
    const float* __restrict__ kA, const float* __restrict__ vA,
    const float* __restrict__ aaA, const float* __restrict__ b2A,
    float* __restrict__ yA)
{
    const int blk = blockIdx.x;          // rg*24 + bh  (XCD swizzle)
    const int bh = blk % 24, rg = blk / 24;
    const int b = bh / HH, h = bh - b * HH;
    const int lane = threadIdx.x;
    const int jg = lane >> 3, p = lane & 7;
    const int row = rg * 8 + p;
    const int base = b * TT * CC + h * NN;
    const int fo = jg * 8;

    float S[8];
#pragma unroll
    for (int i = 0; i < 8; ++i) S[i] = 0.f;

    WFrag f0, f1, f2;

    auto loadfrag = [&](WFrag& f, int t) {
        const int o = base + t * CC + fo;
#pragma unroll
        for (int q = 0; q < 2; ++q) {
            f.w[q] = *(const float4*)&wA[o + 4 * q];
            f.a[q] = *(const float4*)&aaA[o + 4 * q];
            f.b[q] = *(const float4*)&b2A[o + 4 * q];
            f.k[q] = *(const float4*)&kA[o + 4 * q];
            f.r[q] = *(const float4*)&rA[o + 4 * q];
        }
        f.vv = vA[base + t * CC + row];
    };

    auto stepf = [&](const WFrag& f, int t) {
        const float vv = f.vv;
        float vk[8];
#pragma unroll
        for (int q = 0; q < 2; ++q) {
            vk[4*q+0] = vv * f.k[q].x;
            vk[4*q+1] = vv * f.k[q].y;
            vk[4*q+2] = vv * f.k[q].z;
            vk[4*q+3] = vv * f.k[q].w;
        }

        float t0 = 0.f, t1 = 0.f, t2 = 0.f, t3 = 0.f;
#pragma unroll
        for (int q = 0; q < 2; ++q) {
            float4 a4 = f.a[q];
            t0 = fmaf(S[4*q+0], a4.x, t0);
            t1 = fmaf(S[4*q+1], a4.y, t1);
            t2 = fmaf(S[4*q+2], a4.z, t2);
            t3 = fmaf(S[4*q+3], a4.w, t3);
        }
        float part = (t0 + t1) + (t2 + t3);
        float s08 = __shfl_xor(part,  8, 64);
        float s16 = __shfl_xor(part, 16, 64);
        float s24 = __shfl_xor(part, 24, 64);
        float s32 = __shfl_xor(part, 32, 64);
        float s40 = __shfl_xor(part, 40, 64);
        float s48 = __shfl_xor(part, 48, 64);
        float s56 = __shfl_xor(part, 56, 64);
        float tmp = ((part + s08) + (s16 + s24)) + ((s32 + s40) + (s48 + s56));

        float y0 = 0.f, y1 = 0.f, y2 = 0.f, y3 = 0.f;
#pragma unroll
        for (int q = 0; q < 2; ++q) {
            float4 w4 = f.w[q], b4 = f.b[q], r4 = f.r[q];
            S[4*q+0] = fmaf(S[4*q+0], w4.x, fmaf(tmp, b4.x, vk[4*q+0]));
            y0 = fmaf(S[4*q+0], r4.x, y0);
            S[4*q+1] = fmaf(S[4*q+1], w4.y, fmaf(tmp, b4.y, vk[4*q+1]));
            y1 = fmaf(S[4*q+1], r4.y, y1);
            S[4*q+2] = fmaf(S[4*q+2], w4.z, fmaf(tmp, b4.z, vk[4*q+2]));
            y2 = fmaf(S[4*q+2], r4.z, y2);
            S[4*q+3] = fmaf(S[4*q+3], w4.w, fmaf(tmp, b4.w, vk[4*q+3]));
            y3 = fmaf(S[4*q+3], r4.w, y3);
        }
        float yp = (y0 + y1) + (y2 + y3);
        float u08 = __shfl_xor(yp,  8, 64);
        float u16 = __shfl_xor(yp, 16, 64);
        float u24 = __shfl_xor(yp, 24, 64);
        float u32 = __shfl_xor(yp, 32, 64);
        float u40 = __shfl_xor(yp, 40, 64);
        float u48 = __shfl_xor(yp, 48, 64);
        float u56 = __shfl_xor(yp, 56, 64);
        float y = ((yp + u08) + (u16 + u24)) + ((u32 + u40) + (u48 + u56));
        if (jg == 0) yA[base + t * CC + row] = y;
    };

    loadfrag(f0, 0);
    loadfrag(f1, 1);
    loadfrag(f2, 2);

    int t = 0;
    for (; t + 2 < TT; t += 3) {
        stepf(f0, t);
        if (t + 3 < TT) loadfrag(f0, t + 3);
        stepf(f1, t + 1);
        if (t + 4 < TT) loadfrag(f1, t + 4);
        stepf(f2, t + 2);
        if (t + 5 < TT) loadfrag(f2, t + 5);
    }
    if (t < TT) stepf(f0, t);
    if (t + 1 < TT) stepf(f1, t + 1);
}

// ---------------------------------------------------------------------------
// E2: per token: RMSNorm(y)*lnw + (sum_head r*k*faaaa)*v, times g -> bf16 z
// ---------------------------------------------------------------------------
__global__ __launch_bounds__(256) void e2_kernel(
    const float* __restrict__ yA, const float* __restrict__ rA,
    const float* __restrict__ kA, const float* __restrict__ vA,
    const float* __restrict__ gA, const float* __restrict__ faaaa,
    const float* __restrict__ lnw, unsigned short* __restrict__ zB)
{
    const size_t base = (size_t)blockIdx.x * CC;
    const int tid = threadIdx.x;
    const int wave = tid >> 6;
    __shared__ float red[4];
    __shared__ float rk[12];

    float yv[3];
    float ss = 0.f;
#pragma unroll
    for (int ch = 0; ch < 3; ++ch) {
        int c = ch * 256 + tid;
        float y = yA[base + c];
        yv[ch] = y;
        ss = fmaf(y, y, ss);
        float p = rA[base + c] * kA[base + c] * faaaa[c];
#pragma unroll
        for (int off = 32; off; off >>= 1) p += __shfl_xor(p, off, 64);
        if ((tid & 63) == 0) rk[ch * 4 + wave] = p;
    }
#pragma unroll
    for (int off = 32; off; off >>= 1) ss += __shfl_xor(ss, off, 64);
    if ((tid & 63) == 0) red[wave] = ss;
    __syncthreads();
    const float total = red[0] + red[1] + red[2] + red[3];
    const float scale = rsqrtf(total / (float)CC + 1e-5f);
#pragma unroll
    for (int ch = 0; ch < 3; ++ch) {
        int c = ch * 256 + tid;
        float out = yv[ch] * scale * lnw[c] + rk[c >> 6] * vA[base + c];
        zB[base + c] = f2bf(out * gA[base + c]);
    }
}

// ---------------------------------------------------------------------------
extern "C" void kernel_launch(void* const* d_in, const int* in_sizes, int n_in,
                              void* d_out, int out_size, void* d_ws, size_t ws_size,
                              hipStream_t stream)
{
    (void)in_sizes; (void)n_in; (void)out_size; (void)ws_size;
    const float* x        = (const float*)d_in[0];
    const float* tmaa_r   = (const float*)d_in[2];
    const float* tmaa_w   = (const float*)d_in[3];
    const float* tmaa_k   = (const float*)d_in[4];
    const float* tmaa_v   = (const float*)d_in[5];
    const float* tmaa_a   = (const float*)d_in[6];
    const float* tmaa_g   = (const float*)d_in[7];
    const float* tdecay   = (const float*)d_in[8];
    const float* tfaaaa   = (const float*)d_in[9];
    const float* taaaaa   = (const float*)d_in[10];
    const float* maa_w1   = (const float*)d_in[11];
    const float* maa_w2   = (const float*)d_in[12];
    const float* decay_w1 = (const float*)d_in[13];
    const float* decay_w2 = (const float*)d_in[14];
    const float* aaa_w1   = (const float*)d_in[15];
    const float* aaa_w2   = (const float*)d_in[16];
    const float* kkk_w1   = (const float*)d_in[17];
    const float* kkk_w2   = (const float*)d_in[18];
    const float* gate_w1  = (const float*)d_in[19];
    const float* gate_w2  = (const float*)d_in[20];
    const float* w_key    = (const float*)d_in[21];
    const float* w_value  = (const float*)d_in[22];
    const float* w_recept = (const float*)d_in[23];
    const float* w_output = (const float*)d_in[24];
    const float* lnw      = (const float*)d_in[25];
    float* out = (float*)d_out;

    float* ws   = (float*)d_ws;
    float* paux = ws;                 // 6*768
    float* tm   = ws + 8192;          // S1
    float* X6   = tm + S1;            // 6*FF
    float* dh   = X6 + 6 * FF;        // B*64*T = 262144
    float* ah   = dh + 262144;
    float* kh   = ah + 262144;
    float* gh   = kh + 262144;        // B*192*T = 786432
    float* gbuf = gh + 786432;        // FF
    float* ybuf = gbuf + FF;          // FF
    // bf16 region after ybuf
    unsigned short* X6b = (unsigned short*)(ybuf + FF);  // 3*FF bf16 (xr,xk,xv)
    unsigned short* zb  = X6b + 3 * FF;                  // FF bf16
    unsigned short* wb  = zb + FF;                       // 4*2*384*384 bf16

    float* xr = X6 + 0 * FF; float* xw = X6 + 1 * FF; float* xk = X6 + 2 * FF;
    float* xv = X6 + 3 * FF; float* xa = X6 + 4 * FF; float* xg = X6 + 5 * FF;
    float* wwB = X6 + 0 * FF; float* rB  = X6 + 1 * FF; float* aaB = X6 + 2 * FF;
    float* b2B = X6 + 3 * FF; float* kB  = X6 + 4 * FF; float* vB  = X6 + 5 * FF;
    (void)xr; (void)xv;   // replaced by bf16 copies for the MFMA convs

    const long CT = (long)CC * TT;        // 1572864
    const long TC = (long)TT * CC;        // 1572864

    pack_aux_kernel<<<dim3(3), 256, 0, stream>>>(tmaa_r, tmaa_w, tmaa_k, tmaa_v, tmaa_a, tmaa_g, paux);
    wcvt_kernel<<<dim3(4608), 256, 0, stream>>>(w_recept, w_key, w_value, w_output, wb);

    // tm = tanh(maa_w1 @ x)   (B,384,T)
    gemm_kernel<0,0,0,1><<<dim3(32, 6, 2), 256, 0, stream>>>(
        maa_w1, x, tm, nullptr, nullptr,
        768, 768, TT, TT, 1,
        0, 0, CT, 0, 384L * TT, 0, 0, 0, nullptr);

    // X6[n] = x * (paux[n] + maa_w2[n]^T @ tm_n)   z = b*6 + n ; bf16 side-write r/k/v
    gemm_kernel<1,0,0,2><<<dim3(32, 12, 12), 256, 0, stream>>>(
        maa_w2, tm, X6, paux, x,
        64, 768, TT, TT, 6,
        0, 64L * 768, 384L * TT, 64L * TT, CT, FF, 768, CT, X6b);

    // lora hiddens (tanh)
    gemm_kernel<0,0,0,1><<<dim3(32, 1, 2), 256, 0, stream>>>(
        decay_w1, xw, dh, nullptr, nullptr, 768, 768, TT, TT, 1,
        0, 0, CT, 0, 64L * TT, 0, 0, 0, nullptr);
    gemm_kernel<0,0,0,1><<<dim3(32, 1, 2), 256, 0, stream>>>(
        aaa_w1, xa, ah, nullptr, nullptr, 768, 768, TT, TT, 1,
        0, 0, CT, 0, 64L * TT, 0, 0, 0, nullptr);
    gemm_kernel<0,0,0,1><<<dim3(32, 1, 2), 256, 0, stream>>>(
        kkk_w1, xk, kh, nullptr, nullptr, 768, 768, TT, TT, 1,
        0, 0, CT, 0, 64L * TT, 0, 0, 0, nullptr);
    gemm_kernel<0,0,0,1><<<dim3(32, 3, 2), 256, 0, stream>>>(
        gate_w1, xg, gh, nullptr, nullptr, 768, 768, TT, TT, 1,
        0, 0, CT, 0, 192L * TT, 0, 0, 0, nullptr);

    // grouped convs via bf16 MFMA -> (B,T,C) fp32 outputs
    conv_mfma_kernel<0,0><<<dim3(16, 3, 4), 256, 0, stream>>>(wb + 0L * 294912, X6b + 0 * FF, rB);
    conv_mfma_kernel<0,0><<<dim3(16, 3, 4), 256, 0, stream>>>(wb + 1L * 294912, X6b + 1 * FF, kB);
    conv_mfma_kernel<0,0><<<dim3(16, 3, 4), 256, 0, stream>>>(wb + 2L * 294912, X6b + 2 * FF, vB);

    // lora outs -> (B,T,C)
    gemm_kernel<0,0,1,3><<<dim3(32, 12, 2), 256, 0, stream>>>(
        decay_w2, dh, wwB, tdecay, nullptr, 64, 64, TT, CC, 1,
        0, 0, 64L * TT, 0, TC, 0, 0, 0, nullptr);
    gemm_kernel<0,0,1,4><<<dim3(32, 12, 2), 256, 0, stream>>>(
        aaa_w2, ah, b2B /* a for now */, taaaaa, nullptr, 64, 64, TT, CC, 1,
        0, 0, 64L * TT, 0, TC, 0, 0, 0, nullptr);
    gemm_kernel<0,0,1,0><<<dim3(32, 12, 2), 256, 0, stream>>>(
        kkk_w2, kh, aaB /* kvec for now */, nullptr, nullptr, 64, 64, TT, CC, 1,
        0, 0, 64L * TT, 0, TC, 0, 0, 0, nullptr);
    gemm_kernel<0,0,1,0><<<dim3(32, 12, 2), 256, 0, stream>>>(
        gate_w2, gh, gbuf, nullptr, nullptr, 192, 192, TT, CC, 1,
        0, 0, 192L * TT, 0, TC, 0, 0, 0, nullptr);

    // E1: build aa (over kvec slot) and b2 (over a slot)
    e1_kernel<<<dim3(BB * TT), 256, 0, stream>>>(kB, aaB, b2B);

    // WKV recurrence v9: 8-way column split, 192 waves
    wkv_kernel<<<dim3(BB * HH * 8), 64, 0, stream>>>(rB, wwB, kB, vB, aaB, b2B, ybuf);

    // E2: rmsnorm + faaaa bonus + gate -> bf16 z
    e2_kernel<<<dim3(BB * TT), 256, 0, stream>>>(ybuf, rB, kB, vB, gbuf, tfaaaa, lnw, zb);

    // final grouped conv via bf16 MFMA: z (B,T,C) -> out (B,C,T)
    conv_mfma_kernel<1,1><<<dim3(16, 3, 4), 256, 0, stream>>>(wb + 3L * 294912, zb, out);
}

// Round 12
// 1053.718 us; speedup vs baseline: 1.2140x; 1.0041x over previous
//
#include <hip/hip_runtime.h>
#include <math.h>

// Problem constants
#define BB 2
#define TT 2048
#define CC 768
#define HH 12
#define NN 64
#define GG 2
#define CG 384   // C/G
#define FF 3145728L   // B*C*T
#define S1 1572864L   // B*384*T

typedef __attribute__((ext_vector_type(8))) short bf8frag;   // 8 bf16 (4 VGPRs)
typedef __attribute__((ext_vector_type(4))) float f4acc;     // 4 fp32 acc

__device__ inline unsigned short f2bf(float x) {
    union { float f; unsigned u; } v; v.f = x;
    unsigned r = v.u + 0x7FFFu + ((v.u >> 16) & 1u);   // RNE
    return (unsigned short)(r >> 16);
}

// ---------------------------------------------------------------------------
// Generic fp32 tiled GEMM v1: 64x64 tile, 256 threads, 4x4 micro-tile.
// bfout: optional bf16 side-write (mix GEMM emits bf16 xr/xk/xv copies).
// ---------------------------------------------------------------------------
template<int ATRANS, int BTRANS, int TOUT, int MODE>
__global__ __launch_bounds__(256) void gemm_kernel(
    const float* __restrict__ A, const float* __restrict__ Bm, float* __restrict__ Cm,
    const float* __restrict__ aux, const float* __restrict__ aux2,
    int K, int ldA, int ldB, int ldC, int zInner,
    long sA_o, long sA_i, long sB_o, long sB_i, long sC_o, long sC_i,
    long sAux_i, long sAux2_o, unsigned short* bfout)
{
    const int zo = blockIdx.z / zInner;
    const int zi = blockIdx.z % zInner;
    A  += (size_t)zo * sA_o + (size_t)zi * sA_i;
    Bm += (size_t)zo * sB_o + (size_t)zi * sB_i;
    Cm += (size_t)zo * sC_o + (size_t)zi * sC_i;
    if (MODE == 2) { aux += (size_t)zi * sAux_i; aux2 += (size_t)zo * sAux2_o; }

    const int m0t = blockIdx.y * 64;
    const int n0t = blockIdx.x * 64;
    const int tid = threadIdx.x;

    __shared__ float As[16][64];
    __shared__ float Bs[16][64];

    int mi, ni;
    if (TOUT) { mi = (tid & 15) * 4; ni = (tid >> 4) * 4; }
    else      { ni = (tid & 15) * 4; mi = (tid >> 4) * 4; }

    float acc[4][4];
#pragma unroll
    for (int i = 0; i < 4; ++i)
#pragma unroll
        for (int j = 0; j < 4; ++j) acc[i][j] = 0.f;

    for (int k0 = 0; k0 < K; k0 += 16) {
        if (!ATRANS) {
            const int row = tid >> 2;
            const int kc  = (tid & 3) * 4;
            float4 av = *(const float4*)&A[(size_t)(m0t + row) * ldA + k0 + kc];
            As[kc + 0][row] = av.x; As[kc + 1][row] = av.y;
            As[kc + 2][row] = av.z; As[kc + 3][row] = av.w;
        } else {
            const int krow = tid >> 4;
            const int mc   = (tid & 15) * 4;
            *(float4*)&As[krow][mc] = *(const float4*)&A[(size_t)(k0 + krow) * ldA + m0t + mc];
        }
        if (!BTRANS) {
            const int krow = tid >> 4;
            const int tc   = (tid & 15) * 4;
            *(float4*)&Bs[krow][tc] = *(const float4*)&Bm[(size_t)(k0 + krow) * ldB + n0t + tc];
        } else {
            const int trow = tid >> 2;
            const int kc   = (tid & 3) * 4;
            float4 bv = *(const float4*)&Bm[(size_t)(n0t + trow) * ldB + k0 + kc];
            Bs[kc + 0][trow] = bv.x; Bs[kc + 1][trow] = bv.y;
            Bs[kc + 2][trow] = bv.z; Bs[kc + 3][trow] = bv.w;
        }
        __syncthreads();
#pragma unroll
        for (int kk = 0; kk < 16; ++kk) {
            float4 a4 = *(const float4*)&As[kk][mi];
            float4 b4 = *(const float4*)&Bs[kk][ni];
            float am[4] = {a4.x, a4.y, a4.z, a4.w};
            float bn[4] = {b4.x, b4.y, b4.z, b4.w};
#pragma unroll
            for (int i = 0; i < 4; ++i)
#pragma unroll
                for (int j = 0; j < 4; ++j) acc[i][j] = fmaf(am[i], bn[j], acc[i][j]);
        }
        __syncthreads();
    }

    const int mbase = m0t + mi, nbase = n0t + ni;
#pragma unroll
    for (int i = 0; i < 4; ++i) {
        float4 xv;
        if (MODE == 2) xv = *(const float4*)&aux2[(size_t)(mbase + i) * ldC + nbase];
        float xa[4] = {0.f, 0.f, 0.f, 0.f};
        if (MODE == 2) { xa[0] = xv.x; xa[1] = xv.y; xa[2] = xv.z; xa[3] = xv.w; }
#pragma unroll
        for (int j = 0; j < 4; ++j) {
            float v = acc[i][j];
            if (MODE == 1) v = tanhf(v);
            else if (MODE == 2) v = xa[j] * (aux[mbase + i] + v);
            else if (MODE == 3) {
                float u  = aux[mbase + i] + v;
                float sp = fmaxf(-u, 0.f) + log1pf(expf(-fabsf(u)));  // softplus(-u)
                float wl = -sp - 0.5f;
                v = expf(-expf(wl));
            } else if (MODE == 4) {
                float u = aux[mbase + i] + v;
                v = 1.f / (1.f + expf(-u));
            }
            acc[i][j] = v;
        }
    }
    if (!TOUT) {
#pragma unroll
        for (int i = 0; i < 4; ++i) {
            float4 o = {acc[i][0], acc[i][1], acc[i][2], acc[i][3]};
            *(float4*)&Cm[(size_t)(mbase + i) * ldC + nbase] = o;
        }
        // bf16 side-write for MFMA conv inputs: slots n in {0:xr, 2:xk, 3:xv}
        if (MODE == 2 && bfout != nullptr) {
            int sidx = (zi == 0) ? 0 : (zi == 2) ? 1 : (zi == 3) ? 2 : -1;
            if (sidx >= 0) {
                unsigned short* bp = bfout + (size_t)sidx * FF + (size_t)zo * ((long)CC * TT);
#pragma unroll
                for (int i = 0; i < 4; ++i) {
                    ushort4 o = {f2bf(acc[i][0]), f2bf(acc[i][1]), f2bf(acc[i][2]), f2bf(acc[i][3])};
                    *(ushort4*)&bp[(size_t)(mbase + i) * ldC + nbase] = o;
                }
            }
        }
    } else {
#pragma unroll
        for (int j = 0; j < 4; ++j) {
            float4 o = {acc[0][j], acc[1][j], acc[2][j], acc[3][j]};
            *(float4*)&Cm[(size_t)(nbase + j) * ldC + mbase] = o;
        }
    }
}

// ---------------------------------------------------------------------------
// bf16 MFMA grouped-conv GEMM (XT=1 fast path only now): per (b,g),
// C(384x2048) = W(384x384) X(384x2048), X given as (B,T,C) bf16.
// Block = 128c x 128t, 4 waves, 2x8 16x16x32 frags/wave. LDS rows padded
// to 40 (16B aligned). Layouts guide-verified (A[m=lr][k=lq*8+j],
// B[k=lq*8+j][n=lr], D[row=lq*4+i][col=lr]).
//  OUT_CT=0: store (B,T,C) fp32 float4 ; =1: store (B,C,T) scalar (t-coalesced)
// ---------------------------------------------------------------------------
template<int OUT_CT>
__global__ __launch_bounds__(256) void conv_mfma_kernel(
    const unsigned short* __restrict__ Wb, const unsigned short* __restrict__ Xb,
    float* __restrict__ Cout)
{
    const int bz = blockIdx.z; const int b = bz >> 1, g = bz & 1;
    const int t0 = blockIdx.x * 128;
    const int m0 = blockIdx.y * 128;
    const int tid = threadIdx.x;
    const int wave = tid >> 6, lane = tid & 63;
    const int lq = lane >> 4, lr = lane & 15;

    __shared__ unsigned short Ws[128 * 40];
    __shared__ unsigned short Xs[128 * 40];

    const unsigned short* Wg = Wb + (size_t)g * (CG * CG);
    const long xbase = (long)b * (long)TT * CC;

    f4acc acc0[8], acc1[8];
#pragma unroll
    for (int j = 0; j < 8; ++j) { acc0[j] = (f4acc)0.f; acc1[j] = (f4acc)0.f; }

    for (int k0 = 0; k0 < CG; k0 += 32) {
        {
            const int m = tid >> 1, kc = (tid & 1) * 16;
            const unsigned short* src = Wg + (size_t)(m0 + m) * CG + k0 + kc;
            *(bf8frag*)&Ws[m * 40 + kc]     = *(const bf8frag*)src;
            *(bf8frag*)&Ws[m * 40 + kc + 8] = *(const bf8frag*)(src + 8);
        }
        {
            const int t = tid >> 1, kc = (tid & 1) * 16;
            const unsigned short* src = Xb + xbase + (long)(t0 + t) * CC + g * CG + k0 + kc;
            *(bf8frag*)&Xs[t * 40 + kc]     = *(const bf8frag*)src;
            *(bf8frag*)&Xs[t * 40 + kc + 8] = *(const bf8frag*)(src + 8);
        }
        __syncthreads();

        bf8frag a0 = *(const bf8frag*)&Ws[(32 * wave + lr) * 40 + lq * 8];
        bf8frag a1 = *(const bf8frag*)&Ws[(32 * wave + 16 + lr) * 40 + lq * 8];
#pragma unroll
        for (int nj = 0; nj < 8; ++nj) {
            bf8frag bb = *(const bf8frag*)&Xs[(16 * nj + lr) * 40 + lq * 8];
            acc0[nj] = __builtin_amdgcn_mfma_f32_16x16x32_bf16(a0, bb, acc0[nj], 0, 0, 0);
            acc1[nj] = __builtin_amdgcn_mfma_f32_16x16x32_bf16(a1, bb, acc1[nj], 0, 0, 0);
        }
        __syncthreads();
    }

#pragma unroll
    for (int fi = 0; fi < 2; ++fi) {
        const int cbase = m0 + 32 * wave + 16 * fi + lq * 4;
#pragma unroll
        for (int nj = 0; nj < 8; ++nj) {
            const f4acc av = fi ? acc1[nj] : acc0[nj];
            const int t = t0 + 16 * nj + lr;
            if (!OUT_CT) {
                float4 o = {av[0], av[1], av[2], av[3]};
                *(float4*)&Cout[(long)b * (long)TT * CC + (long)t * CC + g * CG + cbase] = o;
            } else {
#pragma unroll
                for (int i = 0; i < 4; ++i)
                    Cout[(long)b * (long)CC * TT + (long)(g * CG + cbase + i) * TT + t] = av[i];
            }
        }
    }
}

// ---------------------------------------------------------------------------
// maa_w1 bf16 MFMA GEMM: tm(b,384,T) = tanh( W(384x768) @ x(b,768,T) ),
// x given transposed as xtb (B,T,768) bf16. Block 128m x 128t, K=768.
// ---------------------------------------------------------------------------
__global__ __launch_bounds__(256) void maaw1_mfma_kernel(
    const unsigned short* __restrict__ Wb, const unsigned short* __restrict__ Xb,
    float* __restrict__ Cout)
{
    const int b = blockIdx.z;
    const int t0 = blockIdx.x * 128;
    const int m0 = blockIdx.y * 128;
    const int tid = threadIdx.x;
    const int wave = tid >> 6, lane = tid & 63;
    const int lq = lane >> 4, lr = lane & 15;

    __shared__ unsigned short Ws[128 * 40];
    __shared__ unsigned short Xs[128 * 40];

    const long xbase = (long)b * (long)TT * CC;

    f4acc acc0[8], acc1[8];
#pragma unroll
    for (int j = 0; j < 8; ++j) { acc0[j] = (f4acc)0.f; acc1[j] = (f4acc)0.f; }

    for (int k0 = 0; k0 < CC; k0 += 32) {
        {
            const int m = tid >> 1, kc = (tid & 1) * 16;
            const unsigned short* src = Wb + (size_t)(m0 + m) * CC + k0 + kc;
            *(bf8frag*)&Ws[m * 40 + kc]     = *(const bf8frag*)src;
            *(bf8frag*)&Ws[m * 40 + kc + 8] = *(const bf8frag*)(src + 8);
        }
        {
            const int t = tid >> 1, kc = (tid & 1) * 16;
            const unsigned short* src = Xb + xbase + (long)(t0 + t) * CC + k0 + kc;
            *(bf8frag*)&Xs[t * 40 + kc]     = *(const bf8frag*)src;
            *(bf8frag*)&Xs[t * 40 + kc + 8] = *(const bf8frag*)(src + 8);
        }
        __syncthreads();

        bf8frag a0 = *(const bf8frag*)&Ws[(32 * wave + lr) * 40 + lq * 8];
        bf8frag a1 = *(const bf8frag*)&Ws[(32 * wave + 16 + lr) * 40 + lq * 8];
#pragma unroll
        for (int nj = 0; nj < 8; ++nj) {
            bf8frag bb = *(const bf8frag*)&Xs[(16 * nj + lr) * 40 + lq * 8];
            acc0[nj] = __builtin_amdgcn_mfma_f32_16x16x32_bf16(a0, bb, acc0[nj], 0, 0, 0);
            acc1[nj] = __builtin_amdgcn_mfma_f32_16x16x32_bf16(a1, bb, acc1[nj], 0, 0, 0);
        }
        __syncthreads();
    }

#pragma unroll
    for (int fi = 0; fi < 2; ++fi) {
        const int m = m0 + 32 * wave + 16 * fi + lq * 4;
#pragma unroll
        for (int nj = 0; nj < 8; ++nj) {
            const f4acc av = fi ? acc1[nj] : acc0[nj];
            const int t = t0 + 16 * nj + lr;
#pragma unroll
            for (int i = 0; i < 4; ++i)
                Cout[(long)b * 384 * TT + (long)(m + i) * TT + t] = tanhf(av[i]);
        }
    }
}

// ---------------------------------------------------------------------------
// Transpose kernels (LDS 64x64 tiles):
//  xtr: fp32 (B,C,T) -> bf16 (B,T,C)   (x -> xtb)
//  btr: bf16 [s](B,C,T) -> bf16 [s](B,T,C)  (X6b -> X6t, s=0..2)
// ---------------------------------------------------------------------------
__global__ __launch_bounds__(256) void xtr_kernel(const float* __restrict__ xin,
                                                  unsigned short* __restrict__ xout)
{
    __shared__ unsigned short L[64][68];
    const int t0 = blockIdx.x * 64, c0 = blockIdx.y * 64, b = blockIdx.z;
    const int tid = threadIdx.x;
    const int lr = tid >> 4, lc = (tid & 15) * 4;
#pragma unroll
    for (int i = 0; i < 4; ++i) {
        int c = lr + i * 16;
        float4 v = *(const float4*)&xin[(size_t)b * CC * TT + (size_t)(c0 + c) * TT + t0 + lc];
        L[c][lc + 0] = f2bf(v.x); L[c][lc + 1] = f2bf(v.y);
        L[c][lc + 2] = f2bf(v.z); L[c][lc + 3] = f2bf(v.w);
    }
    __syncthreads();
#pragma unroll
    for (int i = 0; i < 4; ++i) {
        int t = lr + i * 16;
        ushort4 o = {L[lc + 0][t], L[lc + 1][t], L[lc + 2][t], L[lc + 3][t]};
        *(ushort4*)&xout[(size_t)b * TT * CC + (size_t)(t0 + t) * CC + c0 + lc] = o;
    }
}

__global__ __launch_bounds__(256) void btr_kernel(const unsigned short* __restrict__ xin,
                                                  unsigned short* __restrict__ xout)
{
    __shared__ unsigned short L[64][68];
    const int t0 = blockIdx.x * 64, c0 = blockIdx.y * 64;
    const int s = blockIdx.z >> 1, b = blockIdx.z & 1;
    const int tid = threadIdx.x;
    const int lr = tid >> 4, lc = (tid & 15) * 4;
    const size_t ibase = (size_t)s * FF + (size_t)b * CC * TT;
    const size_t obase = (size_t)s * FF + (size_t)b * TT * CC;
#pragma unroll
    for (int i = 0; i < 4; ++i) {
        int c = lr + i * 16;
        ushort4 v = *(const ushort4*)&xin[ibase + (size_t)(c0 + c) * TT + t0 + lc];
        L[c][lc + 0] = v.x; L[c][lc + 1] = v.y; L[c][lc + 2] = v.z; L[c][lc + 3] = v.w;
    }
    __syncthreads();
#pragma unroll
    for (int i = 0; i < 4; ++i) {
        int t = lr + i * 16;
        ushort4 o = {L[lc + 0][t], L[lc + 1][t], L[lc + 2][t], L[lc + 3][t]};
        *(ushort4*)&xout[obase + (size_t)(t0 + t) * CC + c0 + lc] = o;
    }
}

// ---------------------------------------------------------------------------
// Convert 5 weight tensors to bf16: w_recept,w_key,w_value,w_output (2,384,384)
// and maa_w1 (384,768) — all 294912 elements each.
// ---------------------------------------------------------------------------
__global__ void wcvt_kernel(const float* __restrict__ w0, const float* __restrict__ w1,
                            const float* __restrict__ w2, const float* __restrict__ w3,
                            const float* __restrict__ w4, unsigned short* __restrict__ wb)
{
    const int i = blockIdx.x * 256 + threadIdx.x;   // total 5*294912
    const int which = i / 294912, r = i - which * 294912;
    const float* s = (which == 0) ? w0 : (which == 1) ? w1 : (which == 2) ? w2
                   : (which == 3) ? w3 : w4;
    wb[i] = f2bf(s[r]);
}

// ---------------------------------------------------------------------------
__global__ void pack_aux_kernel(const float* __restrict__ r, const float* __restrict__ w,
                                const float* __restrict__ k, const float* __restrict__ v,
                                const float* __restrict__ a, const float* __restrict__ g,
                                float* __restrict__ paux)
{
    int c = blockIdx.x * blockDim.x + threadIdx.x;
    if (c < CC) {
        paux[0 * CC + c] = 1.f + r[c];
        paux[1 * CC + c] = 1.f + w[c];
        paux[2 * CC + c] = 1.f + k[c];
        paux[3 * CC + c] = 1.f + v[c];
        paux[4 * CC + c] = 1.f + a[c];
        paux[5 * CC + c] = 1.f + g[c];
    }
}

// ---------------------------------------------------------------------------
// E1: per token, kk = k + kvec; per-head L2-normalize; aa=-kkn, b2=kkn*a.
// ---------------------------------------------------------------------------
__global__ __launch_bounds__(256) void e1_kernel(const float* __restrict__ kA,
                                                 float* __restrict__ kvecA,
                                                 float* __restrict__ aA)
{
    const size_t base = (size_t)blockIdx.x * CC;
    const int tid = threadIdx.x;
#pragma unroll
    for (int ch = 0; ch < 3; ++ch) {
        int c = ch * 256 + tid;
        float kk = kA[base + c] + kvecA[base + c];
        float ss = kk * kk;
#pragma unroll
        for (int off = 32; off; off >>= 1) ss += __shfl_xor(ss, off, 64);
        float denom = fmaxf(sqrtf(ss), 1e-12f);
        float kkn = kk / denom;
        float av = aA[base + c];
        kvecA[base + c] = -kkn;       // aa
        aA[base + c]    = kkn * av;   // b2
    }
}

// ---------------------------------------------------------------------------
// WKV-7 recurrence, v9 (frozen, 548us steady): 8-way column split, 192 waves,
// SADDR 32-bit addressing, 3-deep named-fragment prefetch.
// ---------------------------------------------------------------------------
struct WFrag {
    float4 w[2], a[2], b[2], k[2], r[2];
    float vv;
};

__global__ __launch_bounds__(64) void wkv_kernel(
    const float* __restrict__ rA, const float* __restrict__ wA,
    const float* __restrict__ kA, const float* __restrict__ vA,
    const float* __restrict__ aaA, const float* __restrict__ b2A,
    float* __restrict__ yA)
{
    const int blk = blockIdx.x;          // rg*24 + bh  (XCD swizzle)
    const int bh = blk % 24, rg = blk / 24;
    const int b = bh / HH, h = bh - b * HH;
    const int lane = threadIdx.x;
    const int jg = lane >> 3, p = lane & 7;
    const int row = rg * 8 + p;
    const int base = b * TT * CC + h * NN;
    const int fo = jg * 8;

    float S[8];
#pragma unroll
    for (int i = 0; i < 8; ++i) S[i] = 0.f;

    WFrag f0, f1, f2;

    auto loadfrag = [&](WFrag& f, int t) {
        const int o = base + t * CC + fo;
#pragma unroll
        for (int q = 0; q < 2; ++q) {
            f.w[q] = *(const float4*)&wA[o + 4 * q];
            f.a[q] = *(const float4*)&aaA[o + 4 * q];
            f.b[q] = *(const float4*)&b2A[o + 4 * q];
            f.k[q] = *(const float4*)&kA[o + 4 * q];
            f.r[q] = *(const float4*)&rA[o + 4 * q];
        }
        f.vv = vA[base + t * CC + row];
    };

    auto stepf = [&](const WFrag& f, int t) {
        const float vv = f.vv;
        float vk[8];
#pragma unroll
        for (int q = 0; q < 2; ++q) {
            vk[4*q+0] = vv * f.k[q].x;
            vk[4*q+1] = vv * f.k[q].y;
            vk[4*q+2] = vv * f.k[q].z;
            vk[4*q+3] = vv * f.k[q].w;
        }

        float t0 = 0.f, t1 = 0.f, t2 = 0.f, t3 = 0.f;
#pragma unroll
        for (int q = 0; q < 2; ++q) {
            float4 a4 = f.a[q];
            t0 = fmaf(S[4*q+0], a4.x, t0);
            t1 = fmaf(S[4*q+1], a4.y, t1);
            t2 = fmaf(S[4*q+2], a4.z, t2);
            t3 = fmaf(S[4*q+3], a4.w, t3);
        }
        float part = (t0 + t1) + (t2 + t3);
        float s08 = __shfl_xor(part,  8, 64);
        float s16 = __shfl_xor(part, 16, 64);
        float s24 = __shfl_xor(part, 24, 64);
        float s32 = __shfl_xor(part, 32, 64);
        float s40 = __shfl_xor(part, 40, 64);
        float s48 = __shfl_xor(part, 48, 64);
        float s56 = __shfl_xor(part, 56, 64);
        float tmp = ((part + s08) + (s16 + s24)) + ((s32 + s40) + (s48 + s56));

        float y0 = 0.f, y1 = 0.f, y2 = 0.f, y3 = 0.f;
#pragma unroll
        for (int q = 0; q < 2; ++q) {
            float4 w4 = f.w[q], b4 = f.b[q], r4 = f.r[q];
            S[4*q+0] = fmaf(S[4*q+0], w4.x, fmaf(tmp, b4.x, vk[4*q+0]));
            y0 = fmaf(S[4*q+0], r4.x, y0);
            S[4*q+1] = fmaf(S[4*q+1], w4.y, fmaf(tmp, b4.y, vk[4*q+1]));
            y1 = fmaf(S[4*q+1], r4.y, y1);
            S[4*q+2] = fmaf(S[4*q+2], w4.z, fmaf(tmp, b4.z, vk[4*q+2]));
            y2 = fmaf(S[4*q+2], r4.z, y2);
            S[4*q+3] = fmaf(S[4*q+3], w4.w, fmaf(tmp, b4.w, vk[4*q+3]));
            y3 = fmaf(S[4*q+3], r4.w, y3);
        }
        float yp = (y0 + y1) + (y2 + y3);
        float u08 = __shfl_xor(yp,  8, 64);
        float u16 = __shfl_xor(yp, 16, 64);
        float u24 = __shfl_xor(yp, 24, 64);
        float u32 = __shfl_xor(yp, 32, 64);
        float u40 = __shfl_xor(yp, 40, 64);
        float u48 = __shfl_xor(yp, 48, 64);
        float u56 = __shfl_xor(yp, 56, 64);
        float y = ((yp + u08) + (u16 + u24)) + ((u32 + u40) + (u48 + u56));
        if (jg == 0) yA[base + t * CC + row] = y;
    };

    loadfrag(f0, 0);
    loadfrag(f1, 1);
    loadfrag(f2, 2);

    int t = 0;
    for (; t + 2 < TT; t += 3) {
        stepf(f0, t);
        if (t + 3 < TT) loadfrag(f0, t + 3);
        stepf(f1, t + 1);
        if (t + 4 < TT) loadfrag(f1, t + 4);
        stepf(f2, t + 2);
        if (t + 5 < TT) loadfrag(f2, t + 5);
    }
    if (t < TT) stepf(f0, t);
    if (t + 1 < TT) stepf(f1, t + 1);
}

// ---------------------------------------------------------------------------
// E2: per token: RMSNorm(y)*lnw + (sum_head r*k*faaaa)*v, times g -> bf16 z
// ---------------------------------------------------------------------------
__global__ __launch_bounds__(256) void e2_kernel(
    const float* __restrict__ yA, const float* __restrict__ rA,
    const float* __restrict__ kA, const float* __restrict__ vA,
    const float* __restrict__ gA, const float* __restrict__ faaaa,
    const float* __restrict__ lnw, unsigned short* __restrict__ zB)
{
    const size_t base = (size_t)blockIdx.x * CC;
    const int tid = threadIdx.x;
    const int wave = tid >> 6;
    __shared__ float red[4];
    __shared__ float rk[12];

    float yv[3];
    float ss = 0.f;
#pragma unroll
    for (int ch = 0; ch < 3; ++ch) {
        int c = ch * 256 + tid;
        float y = yA[base + c];
        yv[ch] = y;
        ss = fmaf(y, y, ss);
        float p = rA[base + c] * kA[base + c] * faaaa[c];
#pragma unroll
        for (int off = 32; off; off >>= 1) p += __shfl_xor(p, off, 64);
        if ((tid & 63) == 0) rk[ch * 4 + wave] = p;
    }
#pragma unroll
    for (int off = 32; off; off >>= 1) ss += __shfl_xor(ss, off, 64);
    if ((tid & 63) == 0) red[wave] = ss;
    __syncthreads();
    const float total = red[0] + red[1] + red[2] + red[3];
    const float scale = rsqrtf(total / (float)CC + 1e-5f);
#pragma unroll
    for (int ch = 0; ch < 3; ++ch) {
        int c = ch * 256 + tid;
        float out = yv[ch] * scale * lnw[c] + rk[c >> 6] * vA[base + c];
        zB[base + c] = f2bf(out * gA[base + c]);
    }
}

// ---------------------------------------------------------------------------
extern "C" void kernel_launch(void* const* d_in, const int* in_sizes, int n_in,
                              void* d_out, int out_size, void* d_ws, size_t ws_size,
                              hipStream_t stream)
{
    (void)in_sizes; (void)n_in; (void)out_size; (void)ws_size;
    const float* x        = (const float*)d_in[0];
    const float* tmaa_r   = (const float*)d_in[2];
    const float* tmaa_w   = (const float*)d_in[3];
    const float* tmaa_k   = (const float*)d_in[4];
    const float* tmaa_v   = (const float*)d_in[5];
    const float* tmaa_a   = (const float*)d_in[6];
    const float* tmaa_g   = (const float*)d_in[7];
    const float* tdecay   = (const float*)d_in[8];
    const float* tfaaaa   = (const float*)d_in[9];
    const float* taaaaa   = (const float*)d_in[10];
    const float* maa_w1   = (const float*)d_in[11];
    const float* maa_w2   = (const float*)d_in[12];
    const float* decay_w1 = (const float*)d_in[13];
    const float* decay_w2 = (const float*)d_in[14];
    const float* aaa_w1   = (const float*)d_in[15];
    const float* aaa_w2   = (const float*)d_in[16];
    const float* kkk_w1   = (const float*)d_in[17];
    const float* kkk_w2   = (const float*)d_in[18];
    const float* gate_w1  = (const float*)d_in[19];
    const float* gate_w2  = (const float*)d_in[20];
    const float* w_key    = (const float*)d_in[21];
    const float* w_value  = (const float*)d_in[22];
    const float* w_recept = (const float*)d_in[23];
    const float* w_output = (const float*)d_in[24];
    const float* lnw      = (const float*)d_in[25];
    float* out = (float*)d_out;

    float* ws   = (float*)d_ws;
    float* paux = ws;                 // 6*768
    float* tm   = ws + 8192;          // S1
    float* X6   = tm + S1;            // 6*FF
    float* dh   = X6 + 6 * FF;        // B*64*T = 262144
    float* ah   = dh + 262144;
    float* kh   = ah + 262144;
    float* gh   = kh + 262144;        // B*192*T = 786432
    float* gbuf = gh + 786432;        // FF
    float* ybuf = gbuf + FF;          // FF
    // bf16 region after ybuf
    unsigned short* X6b = (unsigned short*)(ybuf + FF);  // 3*FF  (xr,xk,xv bf16 (C,T))
    unsigned short* zb  = X6b + 3 * FF;                  // FF
    unsigned short* wb  = zb + FF;                       // 5*294912
    unsigned short* xtb = wb + 5L * 294912;              // FF    (x bf16 (T,C))
    unsigned short* X6t = xtb + FF;                      // 3*FF  (xr,xk,xv bf16 (T,C))

    float* xw = X6 + 1 * FF; float* xk = X6 + 2 * FF;
    float* xa = X6 + 4 * FF; float* xg = X6 + 5 * FF;
    float* wwB = X6 + 0 * FF; float* rB  = X6 + 1 * FF; float* aaB = X6 + 2 * FF;
    float* b2B = X6 + 3 * FF; float* kB  = X6 + 4 * FF; float* vB  = X6 + 5 * FF;

    const long CT = (long)CC * TT;        // 1572864
    const long TC = (long)TT * CC;        // 1572864

    pack_aux_kernel<<<dim3(3), 256, 0, stream>>>(tmaa_r, tmaa_w, tmaa_k, tmaa_v, tmaa_a, tmaa_g, paux);
    wcvt_kernel<<<dim3(5760), 256, 0, stream>>>(w_recept, w_key, w_value, w_output, maa_w1, wb);
    xtr_kernel<<<dim3(32, 12, 2), 256, 0, stream>>>(x, xtb);

    // tm = tanh(maa_w1 @ x)  via bf16 MFMA
    maaw1_mfma_kernel<<<dim3(16, 3, 2), 256, 0, stream>>>(wb + 4L * 294912, xtb, tm);

    // X6[n] = x * (paux[n] + maa_w2[n]^T @ tm_n)   z = b*6 + n ; bf16 side-write r/k/v
    gemm_kernel<1,0,0,2><<<dim3(32, 12, 12), 256, 0, stream>>>(
        maa_w2, tm, X6, paux, x,
        64, 768, TT, TT, 6,
        0, 64L * 768, 384L * TT, 64L * TT, CT, FF, 768, CT, X6b);

    // transpose bf16 conv inputs (C,T) -> (T,C)
    btr_kernel<<<dim3(32, 12, 6), 256, 0, stream>>>(X6b, X6t);

    // lora hiddens (tanh) — fp32, read xw/xa/xk/xg slots (before convs overwrite)
    gemm_kernel<0,0,0,1><<<dim3(32, 1, 2), 256, 0, stream>>>(
        decay_w1, xw, dh, nullptr, nullptr, 768, 768, TT, TT, 1,
        0, 0, CT, 0, 64L * TT, 0, 0, 0, nullptr);
    gemm_kernel<0,0,0,1><<<dim3(32, 1, 2), 256, 0, stream>>>(
        aaa_w1, xa, ah, nullptr, nullptr, 768, 768, TT, TT, 1,
        0, 0, CT, 0, 64L * TT, 0, 0, 0, nullptr);
    gemm_kernel<0,0,0,1><<<dim3(32, 1, 2), 256, 0, stream>>>(
        kkk_w1, xk, kh, nullptr, nullptr, 768, 768, TT, TT, 1,
        0, 0, CT, 0, 64L * TT, 0, 0, 0, nullptr);
    gemm_kernel<0,0,0,1><<<dim3(32, 3, 2), 256, 0, stream>>>(
        gate_w1, xg, gh, nullptr, nullptr, 768, 768, TT, TT, 1,
        0, 0, CT, 0, 192L * TT, 0, 0, 0, nullptr);

    // grouped convs via bf16 MFMA (fast XT=1 staging) -> (B,T,C) fp32
    conv_mfma_kernel<0><<<dim3(16, 3, 4), 256, 0, stream>>>(wb + 0L * 294912, X6t + 0 * FF, rB);
    conv_mfma_kernel<0><<<dim3(16, 3, 4), 256, 0, stream>>>(wb + 1L * 294912, X6t + 1 * FF, kB);
    conv_mfma_kernel<0><<<dim3(16, 3, 4), 256, 0, stream>>>(wb + 2L * 294912, X6t + 2 * FF, vB);

    // lora outs -> (B,T,C)
    gemm_kernel<0,0,1,3><<<dim3(32, 12, 2), 256, 0, stream>>>(
        decay_w2, dh, wwB, tdecay, nullptr, 64, 64, TT, CC, 1,
        0, 0, 64L * TT, 0, TC, 0, 0, 0, nullptr);
    gemm_kernel<0,0,1,4><<<dim3(32, 12, 2), 256, 0, stream>>>(
        aaa_w2, ah, b2B /* a for now */, taaaaa, nullptr, 64, 64, TT, CC, 1,
        0, 0, 64L * TT, 0, TC, 0, 0, 0, nullptr);
    gemm_kernel<0,0,1,0><<<dim3(32, 12, 2), 256, 0, stream>>>(
        kkk_w2, kh, aaB /* kvec for now */, nullptr, nullptr, 64, 64, TT, CC, 1,
        0, 0, 64L * TT, 0, TC, 0, 0, 0, nullptr);
    gemm_kernel<0,0,1,0><<<dim3(32, 12, 2), 256, 0, stream>>>(
        gate_w2, gh, gbuf, nullptr, nullptr, 192, 192, TT, CC, 1,
        0, 0, 192L * TT, 0, TC, 0, 0, 0, nullptr);

    // E1: build aa (over kvec slot) and b2 (over a slot)
    e1_kernel<<<dim3(BB * TT), 256, 0, stream>>>(kB, aaB, b2B);

    // WKV recurrence v9
    wkv_kernel<<<dim3(BB * HH * 8), 64, 0, stream>>>(rB, wwB, kB, vB, aaB, b2B, ybuf);

    // E2: rmsnorm + faaaa bonus + gate -> bf16 z
    e2_kernel<<<dim3(BB * TT), 256, 0, stream>>>(ybuf, rB, kB, vB, gbuf, tfaaaa, lnw, zb);

    // final grouped conv via bf16 MFMA: z (B,T,C) -> out (B,C,T)
    conv_mfma_kernel<1><<<dim3(16, 3, 4), 256, 0, stream>>>(wb + 3L * 294912, zb, out);
}